// Round 2
// baseline (2083.296 us; speedup 1.0000x reference)
//
#include <hip/hip_runtime.h>

// Problem constants (from reference setup_inputs): B=8, C=2 flow, H=720, W=1280, fp32.
constexpr int B  = 8;
constexpr int H  = 720;
constexpr int W  = 1280;
constexpr int HW = H * W;           // 921600
constexpr int N  = B * HW;          // 7372800 pixels

// ---------------------------------------------------------------------------
// Scatter: one thread per source pixel. Splat w=depth, -fx*w, -fy*w onto the
// 4 corners of (x+fx, y+fy). Invalid (out-of-frame) targets contribute w=0 in
// the reference -> exact no-op -> skip. 12 HW fp32 atomics per valid pixel.
// ---------------------------------------------------------------------------
__global__ __launch_bounds__(256) void dfp_scatter(
    const float* __restrict__ flow,   // (B,2,H,W)
    const float* __restrict__ depth,  // (B,1,H,W)
    float* __restrict__ out,          // (B,2,H,W) accumulates ox/oy
    float* __restrict__ count)        // (B,H,W) in workspace
{
    int t = blockIdx.x * 256 + threadIdx.x;
    if (t >= N) return;

    int b = t / HW;                 // compile-time-constant divisors -> magic mul
    int p = t - b * HW;
    int i = p / W;
    int j = p - i * W;

    const int fbase = b * 2 * HW;
    float fx = flow[fbase + p];
    float fy = flow[fbase + HW + p];
    float d  = depth[t];

    float x2 = (float)j + fx;
    float y2 = (float)i + fy;

    // Reference: valid = x2 in [0, W-1] and y2 in [0, H-1]; w = valid ? d : 0.
    // w==0 contributions are exact no-ops -> skip invalid pixels.
    if (!(x2 >= 0.0f && x2 <= (float)(W - 1) &&
          y2 >= 0.0f && y2 <= (float)(H - 1))) return;

    // For valid pixels floor(x2) already lies in [0, W-1]; clip is a no-op.
    int xL = (int)floorf(x2);
    int yT = (int)floorf(y2);
    int xR = min(xL + 1, W - 1);
    int yB = min(yT + 1, H - 1);

    float w  = d;
    float gx = -fx * w;
    float gy = -fy * w;

    float* ox  = out + fbase;        // (b, 0, :, :)
    float* oy  = out + fbase + HW;   // (b, 1, :, :)
    float* cnt = count + b * HW;

    int n00 = yT * W + xL;
    int n01 = yT * W + xR;
    int n10 = yB * W + xL;
    int n11 = yB * W + xR;

    // unsafeAtomicAdd -> HW global_atomic_add_f32 (no CAS loop).
    unsafeAtomicAdd(&cnt[n00], w);  unsafeAtomicAdd(&ox[n00], gx);  unsafeAtomicAdd(&oy[n00], gy);
    unsafeAtomicAdd(&cnt[n01], w);  unsafeAtomicAdd(&ox[n01], gx);  unsafeAtomicAdd(&oy[n01], gy);
    unsafeAtomicAdd(&cnt[n10], w);  unsafeAtomicAdd(&ox[n10], gx);  unsafeAtomicAdd(&oy[n10], gy);
    unsafeAtomicAdd(&cnt[n11], w);  unsafeAtomicAdd(&ox[n11], gx);  unsafeAtomicAdd(&oy[n11], gy);
}

// ---------------------------------------------------------------------------
// Normalize: out = count > 0 ? out / count : 0. float4-vectorized; HW%4==0 so
// a float4 group never straddles a batch boundary.
// ---------------------------------------------------------------------------
__global__ __launch_bounds__(256) void dfp_normalize(
    float* __restrict__ out, const float* __restrict__ count)
{
    int t = blockIdx.x * 256 + threadIdx.x;   // indexes float4 groups over N
    if (t >= N / 4) return;
    int t4 = t * 4;
    int b  = t4 / HW;
    int p  = t4 - b * HW;

    float4 c = *(const float4*)(count + t4);
    float* ox = out + b * 2 * HW + p;
    float* oy = ox + HW;
    float4 vx = *(const float4*)ox;
    float4 vy = *(const float4*)oy;

    vx.x = (c.x > 0.0f) ? vx.x / c.x : 0.0f;
    vx.y = (c.y > 0.0f) ? vx.y / c.y : 0.0f;
    vx.z = (c.z > 0.0f) ? vx.z / c.z : 0.0f;
    vx.w = (c.w > 0.0f) ? vx.w / c.w : 0.0f;
    vy.x = (c.x > 0.0f) ? vy.x / c.x : 0.0f;
    vy.y = (c.y > 0.0f) ? vy.y / c.y : 0.0f;
    vy.z = (c.z > 0.0f) ? vy.z / c.z : 0.0f;
    vy.w = (c.w > 0.0f) ? vy.w / c.w : 0.0f;

    *(float4*)ox = vx;
    *(float4*)oy = vy;
}

extern "C" void kernel_launch(void* const* d_in, const int* in_sizes, int n_in,
                              void* d_out, int out_size, void* d_ws, size_t ws_size,
                              hipStream_t stream)
{
    const float* flow  = (const float*)d_in[0];   // (8,2,720,1280)
    const float* depth = (const float*)d_in[1];   // (8,1,720,1280)
    float* out   = (float*)d_out;                 // (8,2,720,1280)
    float* count = (float*)d_ws;                  // N floats = 29.5 MB

    // Defensive: never touch memory we don't have (a GPU fault can kill the
    // bench container). Needs N*4 bytes of scratch for the count plane.
    if (ws_size < (size_t)N * sizeof(float)) return;

    // Zero accumulators (d_out/d_ws are poisoned 0xAA before every launch).
    hipMemsetAsync(out,   0, (size_t)2 * N * sizeof(float), stream);
    hipMemsetAsync(count, 0, (size_t)N * sizeof(float),     stream);

    dfp_scatter  <<<(N + 255) / 256,     256, 0, stream>>>(flow, depth, out, count);
    dfp_normalize<<<(N / 4 + 255) / 256, 256, 0, stream>>>(out, count);
}

// Round 3
// 615.708 us; speedup vs baseline: 3.3836x; 3.3836x over previous
//
#include <hip/hip_runtime.h>

// Problem constants: B=8, flow (B,2,H,W), depth (B,1,H,W), fp32.
constexpr int B  = 8;
constexpr int H  = 720;
constexpr int W  = 1280;
constexpr int HW = H * W;           // 921600
constexpr int N  = B * HW;          // 7372800

// Tile geometry: each block owns a TY x TX output tile and reads a
// (TY+2C) x (TX+2C) source region. C=6: a source with fx,fy in [-6,6)
// has all 4 corners within Chebyshev distance 6 (corner offsets are
// floor(f) and floor(f)+1, both in [-6,6]). P(|N(0,1)|>=6) ~ 2e-9.
constexpr int TX = 64;              // 1280 / 64 = 20
constexpr int TY = 48;              // 720  / 48 = 15
constexpr int C  = 6;
constexpr int RW = TX + 2 * C;      // 76
constexpr int RH = TY + 2 * C;      // 60
constexpr int RN = RW * RH;         // 4560
constexpr int TN = TY * TX;         // 3072

// ---------------------------------------------------------------------------
// Outlier pass: exactly handles the (near-nonexistent) sources whose flow
// falls outside [-C, C). Global atomics into zeroed ws planes.
// ---------------------------------------------------------------------------
__global__ __launch_bounds__(256) void dfp_outlier(
    const float* __restrict__ flow, const float* __restrict__ depth,
    float* __restrict__ pcnt, float* __restrict__ pox, float* __restrict__ poy)
{
    int t = blockIdx.x * 256 + threadIdx.x;
    if (t >= N) return;
    int b = t / HW;
    int p = t - b * HW;
    int i = p / W;
    int j = p - i * W;

    const int fbase = b * 2 * HW;
    float fx = flow[fbase + p];
    float fy = flow[fbase + HW + p];

    // Inliers handled by the tile kernel.
    if (fx >= -(float)C && fx < (float)C && fy >= -(float)C && fy < (float)C) return;

    float x2 = (float)j + fx;
    float y2 = (float)i + fy;
    if (!(x2 >= 0.0f && x2 <= (float)(W - 1) &&
          y2 >= 0.0f && y2 <= (float)(H - 1))) return;   // w = 0 -> no-op

    float d  = depth[t];
    int xL = (int)floorf(x2);
    int yT = (int)floorf(y2);
    int xR = min(xL + 1, W - 1);
    int yB = min(yT + 1, H - 1);
    float w = d, gx = -fx * d, gy = -fy * d;

    float* cb = pcnt + b * HW;
    float* xb = pox  + b * HW;
    float* yb = poy  + b * HW;
    int n00 = yT * W + xL, n01 = yT * W + xR, n10 = yB * W + xL, n11 = yB * W + xR;
    unsafeAtomicAdd(&cb[n00], w); unsafeAtomicAdd(&xb[n00], gx); unsafeAtomicAdd(&yb[n00], gy);
    unsafeAtomicAdd(&cb[n01], w); unsafeAtomicAdd(&xb[n01], gx); unsafeAtomicAdd(&yb[n01], gy);
    unsafeAtomicAdd(&cb[n10], w); unsafeAtomicAdd(&xb[n10], gx); unsafeAtomicAdd(&yb[n10], gy);
    unsafeAtomicAdd(&cb[n11], w); unsafeAtomicAdd(&xb[n11], gx); unsafeAtomicAdd(&yb[n11], gy);
}

// ---------------------------------------------------------------------------
// Tile kernel: LDS-privatized scatter + fused flush/normalize.
// Block owns output tile [ty0, ty0+TY) x [tx0, tx0+TX); reads sources in the
// halo-expanded region; LDS-atomic-adds contributions landing in its tile
// (each contribution applied exactly once across blocks); then writes
// normalized output directly (adding the outlier planes).
// ---------------------------------------------------------------------------
__global__ __launch_bounds__(256) void dfp_tile(
    const float* __restrict__ flow, const float* __restrict__ depth,
    const float* __restrict__ pcnt, const float* __restrict__ pox,
    const float* __restrict__ poy, float* __restrict__ out)
{
    __shared__ float s_cnt[TN], s_ox[TN], s_oy[TN];
    const int tid = threadIdx.x;

    for (int k = tid; k < TN; k += 256) { s_cnt[k] = 0.f; s_ox[k] = 0.f; s_oy[k] = 0.f; }
    __syncthreads();

    const int tx0 = blockIdx.x * TX;
    const int ty0 = blockIdx.y * TY;
    const int b   = blockIdx.z;
    const float* fxp = flow + b * 2 * HW;
    const float* fyp = fxp + HW;
    const float* dp  = depth + b * HW;

    for (int k = tid; k < RN; k += 256) {
        int ry = k / RW;                 // RW=76 const -> magic mul
        int rx = k - ry * RW;
        int gy = ty0 - C + ry;
        int gx = tx0 - C + rx;
        if ((unsigned)gy >= (unsigned)H || (unsigned)gx >= (unsigned)W) continue;
        int g = gy * W + gx;

        float fx = fxp[g];
        float fy = fyp[g];
        // Inlier check (outliers handled by dfp_outlier).
        if (!(fx >= -(float)C && fx < (float)C && fy >= -(float)C && fy < (float)C)) continue;

        float x2 = (float)gx + fx;
        float y2 = (float)gy + fy;
        if (!(x2 >= 0.0f && x2 <= (float)(W - 1) &&
              y2 >= 0.0f && y2 <= (float)(H - 1))) continue;  // w = 0

        float d = dp[g];
        int xL = (int)floorf(x2);
        int yT = (int)floorf(y2);
        int xR = min(xL + 1, W - 1);
        int yB = min(yT + 1, H - 1);
        float w = d, gxv = -fx * d, gyv = -fy * d;

        int lxL = xL - tx0, lxR = xR - tx0;
        int lyT = yT - ty0, lyB = yB - ty0;

        // Clamped corners may coincide -> two adds = multiplicity 2, matching ref.
        if ((unsigned)lyT < TY && (unsigned)lxL < TX) {
            int l = lyT * TX + lxL;
            atomicAdd(&s_cnt[l], w); atomicAdd(&s_ox[l], gxv); atomicAdd(&s_oy[l], gyv);
        }
        if ((unsigned)lyT < TY && (unsigned)lxR < TX) {
            int l = lyT * TX + lxR;
            atomicAdd(&s_cnt[l], w); atomicAdd(&s_ox[l], gxv); atomicAdd(&s_oy[l], gyv);
        }
        if ((unsigned)lyB < TY && (unsigned)lxL < TX) {
            int l = lyB * TX + lxL;
            atomicAdd(&s_cnt[l], w); atomicAdd(&s_ox[l], gxv); atomicAdd(&s_oy[l], gyv);
        }
        if ((unsigned)lyB < TY && (unsigned)lxR < TX) {
            int l = lyB * TX + lxR;
            atomicAdd(&s_cnt[l], w); atomicAdd(&s_ox[l], gxv); atomicAdd(&s_oy[l], gyv);
        }
    }
    __syncthreads();

    // Fused flush + outlier-plane add + normalize. Lanes cover full 64-wide
    // rows (TX=64) -> coalesced.
    float* outx = out + b * 2 * HW;
    float* outy = outx + HW;
    const float* cb = pcnt + b * HW;
    const float* xb = pox  + b * HW;
    const float* yb = poy  + b * HW;
    for (int k = tid; k < TN; k += 256) {
        int ly = k >> 6;                 // TX = 64
        int lx = k & 63;
        int g = (ty0 + ly) * W + tx0 + lx;
        float c  = s_cnt[k] + cb[g];
        float vx = s_ox[k]  + xb[g];
        float vy = s_oy[k]  + yb[g];
        bool has = c > 0.0f;
        outx[g] = has ? vx / c : 0.0f;
        outy[g] = has ? vy / c : 0.0f;
    }
}

// ---------------------------------------------------------------------------
// Fallback path (Round-2 proven): used only if ws can't hold 3 planes.
// ---------------------------------------------------------------------------
__global__ __launch_bounds__(256) void dfp_scatter(
    const float* __restrict__ flow, const float* __restrict__ depth,
    float* __restrict__ out, float* __restrict__ count)
{
    int t = blockIdx.x * 256 + threadIdx.x;
    if (t >= N) return;
    int b = t / HW;
    int p = t - b * HW;
    int i = p / W;
    int j = p - i * W;
    const int fbase = b * 2 * HW;
    float fx = flow[fbase + p];
    float fy = flow[fbase + HW + p];
    float d  = depth[t];
    float x2 = (float)j + fx;
    float y2 = (float)i + fy;
    if (!(x2 >= 0.0f && x2 <= (float)(W - 1) &&
          y2 >= 0.0f && y2 <= (float)(H - 1))) return;
    int xL = (int)floorf(x2);
    int yT = (int)floorf(y2);
    int xR = min(xL + 1, W - 1);
    int yB = min(yT + 1, H - 1);
    float w = d, gx = -fx * w, gy = -fy * w;
    float* ox = out + fbase;
    float* oy = out + fbase + HW;
    float* cnt = count + b * HW;
    int n00 = yT * W + xL, n01 = yT * W + xR, n10 = yB * W + xL, n11 = yB * W + xR;
    unsafeAtomicAdd(&cnt[n00], w); unsafeAtomicAdd(&ox[n00], gx); unsafeAtomicAdd(&oy[n00], gy);
    unsafeAtomicAdd(&cnt[n01], w); unsafeAtomicAdd(&ox[n01], gx); unsafeAtomicAdd(&oy[n01], gy);
    unsafeAtomicAdd(&cnt[n10], w); unsafeAtomicAdd(&ox[n10], gx); unsafeAtomicAdd(&oy[n10], gy);
    unsafeAtomicAdd(&cnt[n11], w); unsafeAtomicAdd(&ox[n11], gx); unsafeAtomicAdd(&oy[n11], gy);
}

__global__ __launch_bounds__(256) void dfp_normalize(
    float* __restrict__ out, const float* __restrict__ count)
{
    int t = blockIdx.x * 256 + threadIdx.x;
    if (t >= N / 4) return;
    int t4 = t * 4;
    int b  = t4 / HW;
    int p  = t4 - b * HW;
    float4 c = *(const float4*)(count + t4);
    float* ox = out + b * 2 * HW + p;
    float* oy = ox + HW;
    float4 vx = *(const float4*)ox;
    float4 vy = *(const float4*)oy;
    vx.x = (c.x > 0.0f) ? vx.x / c.x : 0.0f;
    vx.y = (c.y > 0.0f) ? vx.y / c.y : 0.0f;
    vx.z = (c.z > 0.0f) ? vx.z / c.z : 0.0f;
    vx.w = (c.w > 0.0f) ? vx.w / c.w : 0.0f;
    vy.x = (c.x > 0.0f) ? vy.x / c.x : 0.0f;
    vy.y = (c.y > 0.0f) ? vy.y / c.y : 0.0f;
    vy.z = (c.z > 0.0f) ? vy.z / c.z : 0.0f;
    vy.w = (c.w > 0.0f) ? vy.w / c.w : 0.0f;
    *(float4*)ox = vx;
    *(float4*)oy = vy;
}

extern "C" void kernel_launch(void* const* d_in, const int* in_sizes, int n_in,
                              void* d_out, int out_size, void* d_ws, size_t ws_size,
                              hipStream_t stream)
{
    const float* flow  = (const float*)d_in[0];
    const float* depth = (const float*)d_in[1];
    float* out = (float*)d_out;

    if (ws_size >= (size_t)3 * N * sizeof(float)) {
        // Fast path: LDS-privatized tile scatter + exact outlier pass.
        float* pcnt = (float*)d_ws;
        float* pox  = pcnt + N;
        float* poy  = pox + N;
        hipMemsetAsync(pcnt, 0, (size_t)3 * N * sizeof(float), stream);
        dfp_outlier<<<(N + 255) / 256, 256, 0, stream>>>(flow, depth, pcnt, pox, poy);
        dim3 grid(W / TX, H / TY, B);   // 20 x 15 x 8 = 2400 blocks
        dfp_tile<<<grid, 256, 0, stream>>>(flow, depth, pcnt, pox, poy, out);
    } else if (ws_size >= (size_t)N * sizeof(float)) {
        // Fallback: proven Round-2 global-atomic path.
        float* count = (float*)d_ws;
        hipMemsetAsync(out,   0, (size_t)2 * N * sizeof(float), stream);
        hipMemsetAsync(count, 0, (size_t)N * sizeof(float),     stream);
        dfp_scatter  <<<(N + 255) / 256,     256, 0, stream>>>(flow, depth, out, count);
        dfp_normalize<<<(N / 4 + 255) / 256, 256, 0, stream>>>(out, count);
    }
    // else: insufficient workspace — cannot run safely.
}